// Round 7
// baseline (138.083 us; speedup 1.0000x reference)
//
#include <hip/hip_runtime.h>

#define NEG_INF (-__builtin_huge_valf())
#define NEG_INF_BITS 0xFF800000

#define CCH   4                 // c's per LDS chunk
#define HB    4                 // output h rows per wave tile
#define ROWS  (HB + 2)          // 6 (h halo)
#define XSTR  64                // xs row stride (floats)
#define SLOTS 6                 // CCH*ROWS*16 float4 / 64 threads
#define KSTR  12                // padded taps per (o,c): 48 B -> b128-aligned

// Neighbor fetch via DPP within each 16-lane row (wg axis).
// bound_ctrl=false -> row-boundary lanes take `old` = -inf, which IS the
// W padding at wg==0 (row_shr:1) / wg==15 (row_shl:1). Validated exact r1-r6.
template <int CTRL>
__device__ __forceinline__ float dpp_neighbor(float v) {
    return __int_as_float(__builtin_amdgcn_update_dpp(
        (int)NEG_INF_BITS, __float_as_int(v), CTRL, 0xF, 0xF, false));
}

// r6 skeleton with ONE structural change: no SMEM in the hot loop.
// Kernel taps are repacked once into LDS (klds, padded to 12 floats per
// (o,c) so each 9-tap batch reads as b128+b128+b32, wave-uniform broadcast,
// conflict-free). All in-loop memory traffic is now DS-only -> in-order
// completion -> compiler can emit COUNTED lgkmcnt waits instead of the
// full lgkmcnt(0) drains forced by mixing out-of-order SMEM with DS.
// xs reads are additionally software-pipelined one cl ahead (static
// 2-slot register buffer, fully unrolled -> no dynamic indexing/spills).
__global__ __launch_bounds__(64, 4)
void maxplus_conv2d_kernel(const float* __restrict__ x,
                           const float* __restrict__ kern,
                           float* __restrict__ out) {
    __shared__ float xs[CCH * ROWS * XSTR];   // 6144 B
    __shared__ float klds[2 * 64 * KSTR];     // 6144 B

    const int tid = threadIdx.x;        // 0..63
    const int wg  = tid & 15;
    const int hr  = tid >> 4;           // 0..3
    const int w0  = wg << 2;

    const int h_base = blockIdx.x * HB;
    const int b      = blockIdx.y;
    const int o_base = blockIdx.z << 1; // o pair

    // ---- one-time tap repack: klds[oo][c][12], t<9 valid ----
    // (t in {9,10,11} stores a clamped dup of t=8; never read. Clamp keeps
    //  the address in-bounds even if the load is speculated past the mask.)
    {
        const float* kb = kern + (size_t)o_base * 576;
#pragma unroll
        for (int i = 0; i < 24; ++i) {          // 24*64 = 1536 floats
            int idx = i * 64 + tid;
            int oo  = idx / 768;
            int rem = idx - oo * 768;
            int c   = rem / KSTR;
            int t   = rem - c * KSTR;
            int ts  = t < 9 ? t : 8;
            klds[idx] = kb[oo * 576 + c * 9 + ts];
        }
    }
    // visibility handled by the first in-loop __syncthreads()

    // ---- staging slots (chunk-invariant; identical to r6) ----
    const float* xb = x + (size_t)b * 64 * 64 * 64;
    const float* gsrc[SLOTS];
    float*       xdst[SLOTS];
    bool         vmask[SLOTS];
#pragma unroll
    for (int k = 0; k < SLOTS; ++k) {
        int rowid = k * 4 + hr;           // 0..23, each exactly once per wave
        int cl    = rowid / ROWS;
        int r     = rowid - cl * ROWS;
        int gh    = h_base + r - 1;       // -1..64
        bool valid = (unsigned)gh < 64u;
        int  ghc   = valid ? gh : 0;
        gsrc[k]  = xb + ((size_t)cl * 64 + ghc) * 64 + wg * 4;
        xdst[k]  = &xs[rowid * XSTR + wg * 4];
        vmask[k] = valid;
    }

    float acc[2][4];
#pragma unroll
    for (int oo = 0; oo < 2; ++oo)
#pragma unroll
        for (int wi = 0; wi < 4; ++wi)
            acc[oo][wi] = NEG_INF;

    // prefetch chunk 0 (global -> reg; vmcnt domain, fully decoupled)
    float4 R[SLOTS];
#pragma unroll
    for (int k = 0; k < SLOTS; ++k) R[k] = *(const float4*)gsrc[k];

#pragma unroll 1
    for (int cc = 0; cc < 64; cc += CCH) {
        __syncthreads();   // WAR fence: prev chunk's reads before these writes

#pragma unroll
        for (int k = 0; k < SLOTS; ++k) {
            float4 v = R[k];
            if (!vmask[k]) v = make_float4(NEG_INF, NEG_INF, NEG_INF, NEG_INF);
            *(float4*)xdst[k] = v;
        }

        __syncthreads();   // RAW fence: writes visible before cross-lane reads

        if (cc + CCH < 64) {   // next-chunk global prefetch rides under compute
#pragma unroll
            for (int k = 0; k < SLOTS; ++k) {
                gsrc[k] += CCH * 64 * 64;
                R[k] = *(const float4*)gsrc[k];
            }
        }

        // ---- pipelined per-cl compute: xs reads issued one cl ahead ----
        float4 xr[2][3];
#pragma unroll
        for (int r = 0; r < 3; ++r)
            xr[0][r] = *(const float4*)(&xs[(0 * ROWS + hr + r) * XSTR + w0]);

#pragma unroll
        for (int cl = 0; cl < CCH; ++cl) {
            const int cur = cl & 1;

            // taps for this cl: wave-uniform broadcast ds_reads (b128 x2 + b32)
            float kr[2][9];
#pragma unroll
            for (int oo = 0; oo < 2; ++oo) {
                const float* kp = &klds[(oo * 64 + cc + cl) * KSTR];
#pragma unroll
                for (int t = 0; t < 9; ++t) kr[oo][t] = kp[t];
            }

            // prefetch next cl's rows while this cl computes
            if (cl + 1 < CCH) {
#pragma unroll
                for (int r = 0; r < 3; ++r)
                    xr[cur ^ 1][r] = *(const float4*)(
                        &xs[((cl + 1) * ROWS + hr + r) * XSTR + w0]);
            }

            // x window: 3 rows x [DPP edge | w0..w0+3 | DPP edge]
            float xv[3][6];
#pragma unroll
            for (int r = 0; r < 3; ++r) {
                float4 m = xr[cur][r];
                xv[r][0] = dpp_neighbor<0x111>(m.w);  // left edge
                xv[r][1] = m.x; xv[r][2] = m.y; xv[r][3] = m.z; xv[r][4] = m.w;
                xv[r][5] = dpp_neighbor<0x101>(m.x);  // right edge
            }

#pragma unroll
            for (int oo = 0; oo < 2; ++oo) {
                const float* k9 = kr[oo];
#pragma unroll
                for (int wi = 0; wi < 4; ++wi) {
                    float m = acc[oo][wi];
                    // paired -> v_max3_f32: 9 add + 4 max3 + 1 max per out per c
                    float t0 = xv[0][wi + 0] + k9[0];
                    float t1 = xv[0][wi + 1] + k9[1];
                    m = fmaxf(m, fmaxf(t0, t1));
                    t0 = xv[0][wi + 2] + k9[2];
                    t1 = xv[1][wi + 0] + k9[3];
                    m = fmaxf(m, fmaxf(t0, t1));
                    t0 = xv[1][wi + 1] + k9[4];
                    t1 = xv[1][wi + 2] + k9[5];
                    m = fmaxf(m, fmaxf(t0, t1));
                    t0 = xv[2][wi + 0] + k9[6];
                    t1 = xv[2][wi + 1] + k9[7];
                    m = fmaxf(m, fmaxf(t0, t1));
                    m = fmaxf(m, xv[2][wi + 2] + k9[8]);
                    acc[oo][wi] = m;
                }
            }
        }
    }

    const int h = h_base + hr;
#pragma unroll
    for (int oo = 0; oo < 2; ++oo) {
        float4 v = make_float4(acc[oo][0], acc[oo][1], acc[oo][2], acc[oo][3]);
        *(float4*)(out + ((((size_t)b * 64 + (o_base + oo)) * 64 + h) * 64 + w0)) = v;
    }
}

extern "C" void kernel_launch(void* const* d_in, const int* in_sizes, int n_in,
                              void* d_out, int out_size, void* d_ws, size_t ws_size,
                              hipStream_t stream) {
    const float* x    = (const float*)d_in[0];   // [8,64,64,64]
    const float* kern = (const float*)d_in[1];   // [64,64,3,3]
    float* out = (float*)d_out;                  // [8,64,64,64]

    dim3 grid(16, 8, 32);   // h-tiles, b, o-pairs
    dim3 block(64);
    maxplus_conv2d_kernel<<<grid, block, 0, stream>>>(x, kern, out);
}